// Round 11
// baseline (75.860 us; speedup 1.0000x reference)
//
#include <hip/hip_runtime.h>

// GPDGaussian: per-pixel 629x3 conv -> (m, S=R^T diag(s) R, s)
// r11 = r10 + double-buffered cs chunks: section k = {fill chunk k+1 into
// buf[(k+1)&1] ; rotate chunk k from buf[k&1]}, one barrier per section.
// Removes the rot->fill serialization; fill's VALU/trans work overlaps the
// 33-deep rotation FMA chains (r10 post-mortem: VALU issue is at the floor,
// 44us of 84 is stall). pk_f32 is 4cyc (datapath-limited) - kept only for
// instruction-count, not throughput.

#define CCH 34
#define ACH 561
#define HWPIX 4096
#define NPIX 16384
#define PXB 6                   // pixels per block
#define NPRB 3                  // pairs per block
#define NTHR 128
#define CSPP (141 * 16)         // cs bytes per pair per chunk buffer (2256)
#define CBUF (NPRB * CSPP)      // one chunk buffer: 6768 B
#define VROW 36                 // V row-pair stride in dwords (144B)
#define VPX (17 * VROW * 4)     // 2448 B per-pixel V region
#define OFF_S 557056
#define OFF_s 19496960
#define LOG2E 1.4426950408889634f

typedef float    f32x2 __attribute__((ext_vector_type(2)));
typedef _Float16 h2    __attribute__((ext_vector_type(2)));

struct Pairs {
    short i[ACH]; short j[ACH];
    constexpr Pairs() : i(), j() {
        int p = 0;
        for (int a = 0; a < CCH - 1; ++a)
            for (int b = a + 1; b < CCH; ++b) { i[p] = (short)a; j[p] = (short)b; ++p; }
    }
};
__device__ constexpr Pairs PR{};

__device__ __forceinline__ float dot2h(h2 a, h2 b, float c) {
#if __has_builtin(__builtin_amdgcn_fdot2)
    return __builtin_amdgcn_fdot2(a, b, c, false);
#else
    return fmaf((float)a[0], (float)b[0], fmaf((float)a[1], (float)b[1], c));
#endif
}

// Givens rotation on packed rows: Ri' = c*Ri + s*Rj ; Rj' = c*Rj - s*Ri
__device__ __forceinline__ void rot2(f32x2& Ri, f32x2& Rj, f32x2 c2, f32x2 s2) {
    f32x2 t1, t2;
    asm("v_pk_mul_f32 %0, %1, %2" : "=v"(t1) : "v"(s2), "v"(Rj));
    asm("v_pk_mul_f32 %0, %1, %2" : "=v"(t2) : "v"(s2), "v"(Ri));
    asm("v_pk_fma_f32 %0, %1, %2, %3" : "=v"(Ri) : "v"(c2), "v"(Ri), "v"(t1));
    asm("v_pk_fma_f32 %0, %1, %2, %3 neg_lo:[0,0,1] neg_hi:[0,0,1]"
        : "=v"(Rj) : "v"(c2), "v"(Rj), "v"(t2));
}

template <int P0, int P1>
__device__ __forceinline__ void apply_rots(f32x2* R2, const f32x2* cs2) {
    #pragma unroll
    for (int k = P0; k < P1; ++k) {
        f32x2 c2 = cs2[2 * (k - P0)];
        f32x2 s2 = cs2[2 * (k - P0) + 1];
        rot2(R2[PR.i[k]], R2[PR.j[k]], c2, s2);
    }
}

__device__ __forceinline__ float2 cs_of(float wv) {
    // angle = pi*tanh(wv); HW cos/sin take revolutions: tanh(wv)/2
    float e  = __builtin_amdgcn_exp2f((2.0f * LOG2E) * wv);
    float tt = 1.0f - 2.0f * __builtin_amdgcn_rcpf(e + 1.0f);
    float rv = 0.5f * tt;
    return make_float2(__builtin_amdgcn_cosf(rv), __builtin_amdgcn_sinf(rv));
}

// one thread computes BOTH pixels of its pair for angle l -> one b128 write
template <int G0, int LEN>
__device__ __forceinline__ void fill_cs(const float* __restrict__ Wm,
                                        const float* __restrict__ bvec,
                                        const float* xs, char* buf,
                                        int npr, int t) {
    for (int o = t; o < npr * LEN; o += NTHR) {
        int pr = (int)((unsigned)o / (unsigned)LEN);
        int l  = o - pr * LEN;
        int ch = 2 * CCH + G0 + l;
        float w0 = Wm[ch * 3 + 0], w1 = Wm[ch * 3 + 1], w2 = Wm[ch * 3 + 2];
        float bb = bvec[ch];
        int pa = 2 * pr, pb = 2 * pr + 1;       // npx always even
        float2 A = cs_of(fmaf(w0, xs[pa*3+0], fmaf(w1, xs[pa*3+1], w2 * xs[pa*3+2])) + bb);
        float2 B = cs_of(fmaf(w0, xs[pb*3+0], fmaf(w1, xs[pb*3+1], w2 * xs[pb*3+2])) + bb);
        float4 cell; cell.x = A.x; cell.y = B.x; cell.z = A.y; cell.w = B.y;
        *(float4*)(buf + pr * CSPP + l * 16) = cell;   // dense b128
    }
}

__global__ __launch_bounds__(NTHR, 4) void gpd_kernel(
    const float* __restrict__ x,     // (4,3,64,64)
    const float* __restrict__ Wm,    // (629,3)
    const float* __restrict__ bvec,  // (629,)
    float* __restrict__ out)
{
    __shared__ alignas(16) char cbuf[2 * CBUF];         // 13536 B (V overlays)
    __shared__ _Float16 lds_sh[PXB * CCH];              // s in f16
    __shared__ float xs[PXB * 3];

    const int t   = threadIdx.x;
    const int p0  = blockIdx.x * PXB;
    const int npx = min(PXB, NPIX - p0);                // always even
    const int npr = npx >> 1;

    // ---- stage x into LDS ----
    for (int i = t; i < npx * 3; i += NTHR) {
        int px = (int)((unsigned)i / 3u); int c = i - px * 3;
        int p = p0 + px; int b = p >> 12; int hw = p & 4095;
        xs[i] = x[(b * 3 + c) * HWPIX + hw];
    }
    __syncthreads();

    // ---- A: mean + s channels ----
    for (int o = t; o < npx * 68; o += NTHR) {
        int q = (int)((unsigned)o / 68u); int ch = o - q * 68;
        int p = p0 + q; int b = p >> 12; int hw = p & 4095;
        float wv = fmaf(Wm[ch*3+0], xs[q*3+0],
                   fmaf(Wm[ch*3+1], xs[q*3+1], Wm[ch*3+2] * xs[q*3+2])) + bvec[ch];
        if (ch < CCH) {
            out[(size_t)p * CCH + ch] = wv;                       // mean
        } else {
            float e  = __builtin_amdgcn_exp2f(-wv * LOG2E);
            float sg = __builtin_amdgcn_rcpf(1.0f + e);
            float sv = fmaf(999.999f, sg, 0.001f);                // s
            int c = ch - CCH;
            out[OFF_s + (size_t)(b * CCH + c) * HWPIX + hw] = sv;
            lds_sh[q * CCH + c] = (_Float16)sv;
        }
    }

    const int pr = t / CCH;                  // pair within block (0..2)
    const int m  = t - pr * CCH;             // R row owned by this thread
    const bool act = (t < npr * CCH);

    f32x2 R2[CCH];
    #pragma unroll
    for (int k = 0; k < CCH; ++k) { R2[k][0] = (k == m) ? 1.0f : 0.0f; R2[k][1] = R2[k][0]; }

    const f32x2* rp0 = (const f32x2*)(cbuf + pr * CSPP);          // pair base, buf0
    const f32x2* rp1 = (const f32x2*)(cbuf + CBUF + pr * CSPP);   // pair base, buf1

    // ---- software-pipelined chunks: fill k+1 || rotate k, 1 barrier/section ----
    fill_cs<0, 141>(Wm, bvec, xs, cbuf, npr, t);                  // chunk0 -> buf0
    __syncthreads();

    fill_cs<141, 140>(Wm, bvec, xs, cbuf + CBUF, npr, t);         // chunk1 -> buf1
    if (act) apply_rots<0, 141>(R2, rp0);                         // rot chunk0
    __syncthreads();

    fill_cs<281, 140>(Wm, bvec, xs, cbuf, npr, t);                // chunk2 -> buf0
    if (act) apply_rots<141, 281>(R2, rp1);                       // rot chunk1
    __syncthreads();

    fill_cs<421, 140>(Wm, bvec, xs, cbuf + CBUF, npr, t);         // chunk3 -> buf1
    if (act) apply_rots<281, 421>(R2, rp0);                       // rot chunk2
    __syncthreads();

    if (act) apply_rots<421, 561>(R2, rp1);                       // rot chunk3
    __syncthreads();                         // buf readers done (V overlays cbuf)

    // ---- pack R to f16 pairs once; R2 dies here ----
    h2 Rh[CCH];
    #pragma unroll
    for (int n = 0; n < CCH; ++n) {
#if __has_builtin(__builtin_amdgcn_cvt_pkrtz)
        Rh[n] = __builtin_bit_cast(h2, __builtin_amdgcn_cvt_pkrtz(R2[n][0], R2[n][1]));
#else
        h2 hv; hv[0] = (_Float16)R2[n][0]; hv[1] = (_Float16)R2[n][1]; Rh[n] = hv;
#endif
    }

    // ---- phase C in 2 rounds: stage V (3 px), compute their S rows ----
    #pragma unroll
    for (int h = 0; h < 2; ++h) {
        if (act) {
            // rows (2mp,2mp+1) packed per dword; thread m writes half (m&1)
            char* base = cbuf + pr * VPX + (m >> 1) * (VROW * 4) + (m & 1) * 2;
            #pragma unroll
            for (int n = 0; n < CCH; ++n)
                *(_Float16*)(base + n * 4) = Rh[n][h];
        }
        __syncthreads();

        if (act) {
            const int px = 2 * pr + h;
            const unsigned* vb = (const unsigned*)(cbuf + pr * VPX);
            const _Float16* sh = lds_sh + px * CCH;
            float acc[CCH];
            #pragma unroll
            for (int n = 0; n < CCH; ++n) acc[n] = 0.0f;
            for (int mp = 0; mp < 17; ++mp) {
                const unsigned* row = vb + mp * VROW;
                h2 vk = __builtin_bit_cast(h2, row[m]) * *(const h2*)(sh + 2 * mp);
                #pragma unroll
                for (int g = 0; g < 8; ++g) {
                    uint4 rr = *(const uint4*)(row + 4 * g);
                    acc[4*g+0] = dot2h(vk, __builtin_bit_cast(h2, rr.x), acc[4*g+0]);
                    acc[4*g+1] = dot2h(vk, __builtin_bit_cast(h2, rr.y), acc[4*g+1]);
                    acc[4*g+2] = dot2h(vk, __builtin_bit_cast(h2, rr.z), acc[4*g+2]);
                    acc[4*g+3] = dot2h(vk, __builtin_bit_cast(h2, rr.w), acc[4*g+3]);
                }
                uint2 rr2 = *(const uint2*)(row + 32);
                acc[32] = dot2h(vk, __builtin_bit_cast(h2, rr2.x), acc[32]);
                acc[33] = dot2h(vk, __builtin_bit_cast(h2, rr2.y), acc[33]);
            }
            float* os = out + OFF_S + (size_t)(p0 + px) * (CCH * CCH) + m * CCH;
            #pragma unroll
            for (int n2 = 0; n2 < 17; ++n2) {
                float2 v; v.x = acc[2*n2]; v.y = acc[2*n2+1];
                *(float2*)(os + 2 * n2) = v;
            }
        }
        __syncthreads();        // V region reused by round 2
    }
}

extern "C" void kernel_launch(void* const* d_in, const int* in_sizes, int n_in,
                              void* d_out, int out_size, void* d_ws, size_t ws_size,
                              hipStream_t stream) {
    const float* x  = (const float*)d_in[0];
    const float* W  = (const float*)d_in[1];
    const float* bv = (const float*)d_in[2];
    float* out = (float*)d_out;
    const int nblk = (NPIX + PXB - 1) / PXB;   // 2731
    hipLaunchKernelGGL(gpd_kernel, dim3(nblk), dim3(NTHR), 0, stream,
                       x, W, bv, out);
}

// Round 12
// 74.735 us; speedup vs baseline: 1.0151x; 1.0151x over previous
//
#include <hip/hip_runtime.h>

// GPDGaussian: per-pixel 629x3 conv -> (m, S=R^T diag(s) R, s)
// r12 = r11 structure + two register fixes:
//  - __launch_bounds__(128, 2): 2nd arg is min WAVES PER EU -> (128,4) capped
//    VGPRs at 64 since r5, forcing R2 (68 regs) into AGPR homes.
//  - rot2 via __builtin_elementwise_fma (v_pk_fma_f32), no inline asm: the
//    asm "v" constraints forced v_accvgpr_read/write around every rotation
//    (~2x VALU issue, the mystery factor measured in r3/r10).

#define CCH 34
#define ACH 561
#define HWPIX 4096
#define NPIX 16384
#define PXB 6                   // pixels per block
#define NPRB 3                  // pairs per block
#define NTHR 128
#define CSPP (141 * 16)         // cs bytes per pair per chunk buffer (2256)
#define CBUF (NPRB * CSPP)      // one chunk buffer: 6768 B
#define VROW 36                 // V row-pair stride in dwords (144B)
#define VPX (17 * VROW * 4)     // 2448 B per-pixel V region
#define OFF_S 557056
#define OFF_s 19496960
#define LOG2E 1.4426950408889634f

typedef float    f32x2 __attribute__((ext_vector_type(2)));
typedef _Float16 h2    __attribute__((ext_vector_type(2)));

struct Pairs {
    short i[ACH]; short j[ACH];
    constexpr Pairs() : i(), j() {
        int p = 0;
        for (int a = 0; a < CCH - 1; ++a)
            for (int b = a + 1; b < CCH; ++b) { i[p] = (short)a; j[p] = (short)b; ++p; }
    }
};
__device__ constexpr Pairs PR{};

__device__ __forceinline__ float dot2h(h2 a, h2 b, float c) {
#if __has_builtin(__builtin_amdgcn_fdot2)
    return __builtin_amdgcn_fdot2(a, b, c, false);
#else
    return fmaf((float)a[0], (float)b[0], fmaf((float)a[1], (float)b[1], c));
#endif
}

// Givens rotation on packed rows: Ri' = c*Ri + s*Rj ; Rj' = c*Rj - s*Ri
// Plain vector ops: LLVM selects v_pk_fma_f32 / v_pk_mul_f32; no register
// constraints -> no accvgpr marshalling.
__device__ __forceinline__ void rot2(f32x2& Ri, f32x2& Rj, f32x2 c2, f32x2 s2) {
    f32x2 t1 = s2 * Rj;
    f32x2 t2 = s2 * Ri;
    Ri = __builtin_elementwise_fma(c2, Ri, t1);
    Rj = __builtin_elementwise_fma(c2, Rj, -t2);
}

template <int P0, int P1>
__device__ __forceinline__ void apply_rots(f32x2* R2, const f32x2* cs2) {
    #pragma unroll
    for (int k = P0; k < P1; ++k) {
        f32x2 c2 = cs2[2 * (k - P0)];
        f32x2 s2 = cs2[2 * (k - P0) + 1];
        rot2(R2[PR.i[k]], R2[PR.j[k]], c2, s2);
    }
}

__device__ __forceinline__ float2 cs_of(float wv) {
    // angle = pi*tanh(wv); HW cos/sin take revolutions: tanh(wv)/2
    float e  = __builtin_amdgcn_exp2f((2.0f * LOG2E) * wv);
    float tt = 1.0f - 2.0f * __builtin_amdgcn_rcpf(e + 1.0f);
    float rv = 0.5f * tt;
    return make_float2(__builtin_amdgcn_cosf(rv), __builtin_amdgcn_sinf(rv));
}

// one thread computes BOTH pixels of its pair for angle l -> one b128 write
template <int G0, int LEN>
__device__ __forceinline__ void fill_cs(const float* __restrict__ Wm,
                                        const float* __restrict__ bvec,
                                        const float* xs, char* buf,
                                        int npr, int t) {
    for (int o = t; o < npr * LEN; o += NTHR) {
        int pr = (int)((unsigned)o / (unsigned)LEN);
        int l  = o - pr * LEN;
        int ch = 2 * CCH + G0 + l;
        float w0 = Wm[ch * 3 + 0], w1 = Wm[ch * 3 + 1], w2 = Wm[ch * 3 + 2];
        float bb = bvec[ch];
        int pa = 2 * pr, pb = 2 * pr + 1;       // npx always even
        float2 A = cs_of(fmaf(w0, xs[pa*3+0], fmaf(w1, xs[pa*3+1], w2 * xs[pa*3+2])) + bb);
        float2 B = cs_of(fmaf(w0, xs[pb*3+0], fmaf(w1, xs[pb*3+1], w2 * xs[pb*3+2])) + bb);
        float4 cell; cell.x = A.x; cell.y = B.x; cell.z = A.y; cell.w = B.y;
        *(float4*)(buf + pr * CSPP + l * 16) = cell;   // dense b128
    }
}

__global__ __launch_bounds__(NTHR, 2) void gpd_kernel(
    const float* __restrict__ x,     // (4,3,64,64)
    const float* __restrict__ Wm,    // (629,3)
    const float* __restrict__ bvec,  // (629,)
    float* __restrict__ out)
{
    __shared__ alignas(16) char cbuf[2 * CBUF];         // 13536 B (V overlays)
    __shared__ _Float16 lds_sh[PXB * CCH];              // s in f16
    __shared__ float xs[PXB * 3];

    const int t   = threadIdx.x;
    const int p0  = blockIdx.x * PXB;
    const int npx = min(PXB, NPIX - p0);                // always even
    const int npr = npx >> 1;

    // ---- stage x into LDS ----
    for (int i = t; i < npx * 3; i += NTHR) {
        int px = (int)((unsigned)i / 3u); int c = i - px * 3;
        int p = p0 + px; int b = p >> 12; int hw = p & 4095;
        xs[i] = x[(b * 3 + c) * HWPIX + hw];
    }
    __syncthreads();

    // ---- A: mean + s channels ----
    for (int o = t; o < npx * 68; o += NTHR) {
        int q = (int)((unsigned)o / 68u); int ch = o - q * 68;
        int p = p0 + q; int b = p >> 12; int hw = p & 4095;
        float wv = fmaf(Wm[ch*3+0], xs[q*3+0],
                   fmaf(Wm[ch*3+1], xs[q*3+1], Wm[ch*3+2] * xs[q*3+2])) + bvec[ch];
        if (ch < CCH) {
            out[(size_t)p * CCH + ch] = wv;                       // mean
        } else {
            float e  = __builtin_amdgcn_exp2f(-wv * LOG2E);
            float sg = __builtin_amdgcn_rcpf(1.0f + e);
            float sv = fmaf(999.999f, sg, 0.001f);                // s
            int c = ch - CCH;
            out[OFF_s + (size_t)(b * CCH + c) * HWPIX + hw] = sv;
            lds_sh[q * CCH + c] = (_Float16)sv;
        }
    }

    const int pr = t / CCH;                  // pair within block (0..2)
    const int m  = t - pr * CCH;             // R row owned by this thread
    const bool act = (t < npr * CCH);

    f32x2 R2[CCH];
    #pragma unroll
    for (int k = 0; k < CCH; ++k) { R2[k][0] = (k == m) ? 1.0f : 0.0f; R2[k][1] = R2[k][0]; }

    const f32x2* rp0 = (const f32x2*)(cbuf + pr * CSPP);          // pair base, buf0
    const f32x2* rp1 = (const f32x2*)(cbuf + CBUF + pr * CSPP);   // pair base, buf1

    // ---- software-pipelined chunks: fill k+1 || rotate k, 1 barrier/section ----
    fill_cs<0, 141>(Wm, bvec, xs, cbuf, npr, t);                  // chunk0 -> buf0
    __syncthreads();

    fill_cs<141, 140>(Wm, bvec, xs, cbuf + CBUF, npr, t);         // chunk1 -> buf1
    if (act) apply_rots<0, 141>(R2, rp0);                         // rot chunk0
    __syncthreads();

    fill_cs<281, 140>(Wm, bvec, xs, cbuf, npr, t);                // chunk2 -> buf0
    if (act) apply_rots<141, 281>(R2, rp1);                       // rot chunk1
    __syncthreads();

    fill_cs<421, 140>(Wm, bvec, xs, cbuf + CBUF, npr, t);         // chunk3 -> buf1
    if (act) apply_rots<281, 421>(R2, rp0);                       // rot chunk2
    __syncthreads();

    if (act) apply_rots<421, 561>(R2, rp1);                       // rot chunk3
    __syncthreads();                         // buf readers done (V overlays cbuf)

    // ---- pack R to f16 pairs once; R2 dies here ----
    h2 Rh[CCH];
    #pragma unroll
    for (int n = 0; n < CCH; ++n) {
#if __has_builtin(__builtin_amdgcn_cvt_pkrtz)
        Rh[n] = __builtin_bit_cast(h2, __builtin_amdgcn_cvt_pkrtz(R2[n][0], R2[n][1]));
#else
        h2 hv; hv[0] = (_Float16)R2[n][0]; hv[1] = (_Float16)R2[n][1]; Rh[n] = hv;
#endif
    }

    // ---- phase C in 2 rounds: stage V (3 px), compute their S rows ----
    #pragma unroll
    for (int h = 0; h < 2; ++h) {
        if (act) {
            // rows (2mp,2mp+1) packed per dword; thread m writes half (m&1)
            char* base = cbuf + pr * VPX + (m >> 1) * (VROW * 4) + (m & 1) * 2;
            #pragma unroll
            for (int n = 0; n < CCH; ++n)
                *(_Float16*)(base + n * 4) = Rh[n][h];
        }
        __syncthreads();

        if (act) {
            const int px = 2 * pr + h;
            const unsigned* vb = (const unsigned*)(cbuf + pr * VPX);
            const _Float16* sh = lds_sh + px * CCH;
            float acc[CCH];
            #pragma unroll
            for (int n = 0; n < CCH; ++n) acc[n] = 0.0f;
            for (int mp = 0; mp < 17; ++mp) {
                const unsigned* row = vb + mp * VROW;
                h2 vk = __builtin_bit_cast(h2, row[m]) * *(const h2*)(sh + 2 * mp);
                #pragma unroll
                for (int g = 0; g < 8; ++g) {
                    uint4 rr = *(const uint4*)(row + 4 * g);
                    acc[4*g+0] = dot2h(vk, __builtin_bit_cast(h2, rr.x), acc[4*g+0]);
                    acc[4*g+1] = dot2h(vk, __builtin_bit_cast(h2, rr.y), acc[4*g+1]);
                    acc[4*g+2] = dot2h(vk, __builtin_bit_cast(h2, rr.z), acc[4*g+2]);
                    acc[4*g+3] = dot2h(vk, __builtin_bit_cast(h2, rr.w), acc[4*g+3]);
                }
                uint2 rr2 = *(const uint2*)(row + 32);
                acc[32] = dot2h(vk, __builtin_bit_cast(h2, rr2.x), acc[32]);
                acc[33] = dot2h(vk, __builtin_bit_cast(h2, rr2.y), acc[33]);
            }
            float* os = out + OFF_S + (size_t)(p0 + px) * (CCH * CCH) + m * CCH;
            #pragma unroll
            for (int n2 = 0; n2 < 17; ++n2) {
                float2 v; v.x = acc[2*n2]; v.y = acc[2*n2+1];
                *(float2*)(os + 2 * n2) = v;
            }
        }
        __syncthreads();        // V region reused by round 2
    }
}

extern "C" void kernel_launch(void* const* d_in, const int* in_sizes, int n_in,
                              void* d_out, int out_size, void* d_ws, size_t ws_size,
                              hipStream_t stream) {
    const float* x  = (const float*)d_in[0];
    const float* W  = (const float*)d_in[1];
    const float* bv = (const float*)d_in[2];
    float* out = (float*)d_out;
    const int nblk = (NPIX + PXB - 1) / PXB;   // 2731
    hipLaunchKernelGGL(gpd_kernel, dim3(nblk), dim3(NTHR), 0, stream,
                       x, W, bv, out);
}